// Round 3
// baseline (7318.711 us; speedup 1.0000x reference)
//
#include <hip/hip_runtime.h>

#define D_MODEL 1024
#define NUM_HEADS 16
#define D_K 64
#define BATCH 2
#define SEQ 2048
#define TQ 8

// ---------------------------------------------------------------------------
// Tiled fp32 GEMM: C[M,1024] = A[M,1024] @ W[1024,1024] + bias[1024]
// 128x128 tile per 256-thread block, 8x8 micro-tile per thread, K-tile = 16.
// 4 ds_read_b128 per 64 FMA (vs 4x4 tile's ~35cyc LDS per 32cyc FMA).
// ---------------------------------------------------------------------------
__global__ __launch_bounds__(256, 2)
void gemm_bias_kernel(const float* __restrict__ A, const float* __restrict__ W,
                      const float* __restrict__ bias, float* __restrict__ C) {
    __shared__ float As[16][128];   // [k][row] (transposed for broadcast reads)
    __shared__ float Bs[16][128];   // [k][col]

    const int tid = threadIdx.x;
    const int tx = tid & 15;        // 0..15 -> col group (8 cols each)
    const int ty = tid >> 4;        // 0..15 -> row group (8 rows each)
    const int rowBase = blockIdx.y * 128;
    const int colBase = blockIdx.x * 128;

    // staging-load indices: A: 128 rows x 16 k, B: 16 k x 128 cols, 8 floats/thread each
    const int ar = tid >> 1;            // 0..127 A-tile row
    const int ac = (tid & 1) * 8;       // 0 or 8  A-tile k-offset
    const int br = tid >> 4;            // 0..15  W-tile k-row
    const int bc = (tid & 15) * 8;      // 0..120 W-tile col

    float acc[8][8] = {};

    for (int k0 = 0; k0 < D_MODEL; k0 += 16) {
        const float* Ar = A + (size_t)(rowBase + ar) * D_MODEL + k0 + ac;
        const float* Wr = W + (size_t)(k0 + br) * D_MODEL + colBase + bc;
        const float4 a0 = *(const float4*)(Ar + 0);
        const float4 a1 = *(const float4*)(Ar + 4);
        const float4 b0 = *(const float4*)(Wr + 0);
        const float4 b1 = *(const float4*)(Wr + 4);
        __syncthreads();   // previous iteration's LDS reads must finish
        As[ac + 0][ar] = a0.x; As[ac + 1][ar] = a0.y;
        As[ac + 2][ar] = a0.z; As[ac + 3][ar] = a0.w;
        As[ac + 4][ar] = a1.x; As[ac + 5][ar] = a1.y;
        As[ac + 6][ar] = a1.z; As[ac + 7][ar] = a1.w;
        *(float4*)&Bs[br][bc + 0] = b0;
        *(float4*)&Bs[br][bc + 4] = b1;
        __syncthreads();
#pragma unroll
        for (int kk = 0; kk < 16; ++kk) {
            const float4 xa0 = *(const float4*)&As[kk][ty * 8 + 0];
            const float4 xa1 = *(const float4*)&As[kk][ty * 8 + 4];
            const float4 xb0 = *(const float4*)&Bs[kk][tx * 8 + 0];
            const float4 xb1 = *(const float4*)&Bs[kk][tx * 8 + 4];
            const float a[8] = {xa0.x, xa0.y, xa0.z, xa0.w, xa1.x, xa1.y, xa1.z, xa1.w};
            const float bcol[8] = {xb0.x, xb0.y, xb0.z, xb0.w, xb1.x, xb1.y, xb1.z, xb1.w};
#pragma unroll
            for (int i = 0; i < 8; ++i)
#pragma unroll
                for (int j = 0; j < 8; ++j)
                    acc[i][j] += a[i] * bcol[j];
        }
    }

    const float4 bb0 = *(const float4*)(bias + colBase + tx * 8 + 0);
    const float4 bb1 = *(const float4*)(bias + colBase + tx * 8 + 4);
#pragma unroll
    for (int i = 0; i < 8; ++i) {
        float4 o0, o1;
        o0.x = acc[i][0] + bb0.x; o0.y = acc[i][1] + bb0.y;
        o0.z = acc[i][2] + bb0.z; o0.w = acc[i][3] + bb0.w;
        o1.x = acc[i][4] + bb1.x; o1.y = acc[i][5] + bb1.y;
        o1.z = acc[i][6] + bb1.z; o1.w = acc[i][7] + bb1.w;
        float* Cr = C + (size_t)(rowBase + ty * 8 + i) * D_MODEL + colBase + tx * 8;
        *(float4*)(Cr + 0) = o0;
        *(float4*)(Cr + 4) = o1;
    }
}

// ---------------------------------------------------------------------------
// Attention: one block per (b, h, 8 query rows). 512 threads (8 waves).
// Register-budgeted: Q fragment per d-chunk is 8 floats (64 VGPR total),
// not 16 (128 VGPR -> spilled in round 1).
// ---------------------------------------------------------------------------
__global__ __launch_bounds__(512, 2)
void attn_kernel(const float* __restrict__ Qp, const float* __restrict__ Kp,
                 const float* __restrict__ Vp, float* __restrict__ attn,
                 float* __restrict__ ctx) {
    const int b  = blockIdx.z;
    const int h  = blockIdx.y;
    const int q0 = blockIdx.x * TQ;
    const int tid  = threadIdx.x;
    const int lane = tid & 63;
    const int wid  = tid >> 6;

    __shared__ float qv[TQ][64];        // 2 KB
    __shared__ float sc[TQ][SEQ];       // 64 KB un-normalized exp; reused as PV-reduce buffer
    __shared__ float wredm[TQ][8];      // per-wave max partials
    __shared__ float wreds[TQ][8];      // per-wave sum partials

    // ---- load 8 query vectors (512 threads = 8*64 elements) ----
    {
        const int q = tid >> 6, d = tid & 63;
        qv[q][d] = Qp[((size_t)(b * SEQ + q0 + q)) * D_MODEL + h * 64 + d];
    }
    __syncthreads();

    // ---- scores: each thread computes 4 k-columns (tid + 512*i) for all 8 rows ----
    float loc[TQ][4];
#pragma unroll
    for (int q = 0; q < TQ; ++q)
#pragma unroll
        for (int i = 0; i < 4; ++i) loc[q][i] = 0.f;

    const float* Kb = Kp + ((size_t)b * SEQ) * D_MODEL + h * 64;
#pragma unroll
    for (int dc = 0; dc < 64; dc += 8) {
        // broadcast Q fragment for this 8-wide d-chunk (conflict-free LDS broadcast)
        float4 qa[TQ], qb[TQ];
#pragma unroll
        for (int q = 0; q < TQ; ++q) {
            qa[q] = *(const float4*)&qv[q][dc + 0];
            qb[q] = *(const float4*)&qv[q][dc + 4];
        }
#pragma unroll
        for (int i = 0; i < 4; ++i) {
            const float* Kr = Kb + (size_t)(tid + i * 512) * D_MODEL + dc;
            const float4 ka = *(const float4*)(Kr + 0);
            const float4 kb = *(const float4*)(Kr + 4);
#pragma unroll
            for (int q = 0; q < TQ; ++q) {
                loc[q][i] += qa[q].x * ka.x + qa[q].y * ka.y +
                             qa[q].z * ka.z + qa[q].w * ka.w +
                             qb[q].x * kb.x + qb[q].y * kb.y +
                             qb[q].z * kb.z + qb[q].w * kb.w;
            }
        }
    }
    const float scale = 0.125f;   // 1/sqrt(64)
#pragma unroll
    for (int q = 0; q < TQ; ++q)
#pragma unroll
        for (int i = 0; i < 4; ++i) loc[q][i] *= scale;

    // ---- row max: thread-local -> wave shuffle -> cross-wave via LDS ----
    float m[TQ];
#pragma unroll
    for (int q = 0; q < TQ; ++q) {
        float lm = fmaxf(fmaxf(loc[q][0], loc[q][1]), fmaxf(loc[q][2], loc[q][3]));
#pragma unroll
        for (int st = 32; st > 0; st >>= 1) lm = fmaxf(lm, __shfl_xor(lm, st, 64));
        if (lane == 0) wredm[q][wid] = lm;
    }
    __syncthreads();
#pragma unroll
    for (int q = 0; q < TQ; ++q) {
        float mm = wredm[q][0];
#pragma unroll
        for (int w = 1; w < 8; ++w) mm = fmaxf(mm, wredm[q][w]);
        m[q] = mm;
    }

    // ---- exp, stash un-normalized in LDS, row-sum ----
#pragma unroll
    for (int q = 0; q < TQ; ++q) {
        float ls = 0.f;
#pragma unroll
        for (int i = 0; i < 4; ++i) {
            const float e = __expf(loc[q][i] - m[q]);
            loc[q][i] = e;
            sc[q][tid + i * 512] = e;
            ls += e;
        }
#pragma unroll
        for (int st = 32; st > 0; st >>= 1) ls += __shfl_xor(ls, st, 64);
        if (lane == 0) wreds[q][wid] = ls;
    }
    __syncthreads();
    float inv[TQ];
#pragma unroll
    for (int q = 0; q < TQ; ++q) {
        float ss = wreds[q][0];
#pragma unroll
        for (int w = 1; w < 8; ++w) ss += wreds[q][w];
        inv[q] = 1.0f / ss;
    }

    // ---- write normalized attn (wave-coalesced 256B stores) ----
#pragma unroll
    for (int q = 0; q < TQ; ++q) {
        const size_t base = (((size_t)(b * NUM_HEADS + h)) * SEQ + (q0 + q)) * (size_t)SEQ;
#pragma unroll
        for (int i = 0; i < 4; ++i)
            attn[base + tid + i * 512] = loc[q][i] * inv[q];
    }

    // ---- fused PV: thread owns 8q x 4d over a 64-wide k slice ----
    const int d4 = (tid & 15) * 4;      // 0..60
    const int kg = tid >> 4;            // 0..31 k-group, 64 k each
    float acc[TQ][4];
#pragma unroll
    for (int q = 0; q < TQ; ++q)
#pragma unroll
        for (int j = 0; j < 4; ++j) acc[q][j] = 0.f;

    const float* Vb = Vp + ((size_t)b * SEQ) * D_MODEL + h * 64 + d4;
#pragma unroll 4
    for (int ks = 0; ks < 64; ks += 4) {
        const int k = kg * 64 + ks;
        const float4 vv0 = *(const float4*)(Vb + (size_t)(k + 0) * D_MODEL);
        const float4 vv1 = *(const float4*)(Vb + (size_t)(k + 1) * D_MODEL);
        const float4 vv2 = *(const float4*)(Vb + (size_t)(k + 2) * D_MODEL);
        const float4 vv3 = *(const float4*)(Vb + (size_t)(k + 3) * D_MODEL);
#pragma unroll
        for (int q = 0; q < TQ; ++q) {
            const float4 p = *(const float4*)&sc[q][k];
            acc[q][0] += p.x * vv0.x + p.y * vv1.x + p.z * vv2.x + p.w * vv3.x;
            acc[q][1] += p.x * vv0.y + p.y * vv1.y + p.z * vv2.y + p.w * vv3.y;
            acc[q][2] += p.x * vv0.z + p.y * vv1.z + p.z * vv2.z + p.w * vv3.z;
            acc[q][3] += p.x * vv0.w + p.y * vv1.w + p.z * vv2.w + p.w * vv3.w;
        }
    }

    // ---- reduce the 32 k-groups through LDS (reuse sc: exactly 16384 floats) ----
    __syncthreads();   // all sc reads done
    float* red = &sc[0][0];             // red[kg][q][d] = [32][8][64]
#pragma unroll
    for (int q = 0; q < TQ; ++q) {
        float4 o;
        o.x = acc[q][0]; o.y = acc[q][1]; o.z = acc[q][2]; o.w = acc[q][3];
        *(float4*)&red[((size_t)kg * TQ + q) * 64 + d4] = o;
    }
    __syncthreads();
    {
        const int q = tid >> 6, d = tid & 63;
        float s = 0.f;
#pragma unroll
        for (int g = 0; g < 32; ++g) s += red[((size_t)g * TQ + q) * 64 + d];
        ctx[((size_t)(b * SEQ + q0 + q)) * D_MODEL + h * 64 + d] = s * inv[q];
    }
}

// ---------------------------------------------------------------------------
extern "C" void kernel_launch(void* const* d_in, const int* in_sizes, int n_in,
                              void* d_out, int out_size, void* d_ws, size_t ws_size,
                              hipStream_t stream) {
    const float* query = (const float*)d_in[0];
    const float* key   = (const float*)d_in[1];
    const float* value = (const float*)d_in[2];
    const float* Wq = (const float*)d_in[3];
    const float* bq = (const float*)d_in[4];
    const float* Wk = (const float*)d_in[5];
    const float* bk = (const float*)d_in[6];
    const float* Wv = (const float*)d_in[7];
    const float* bv = (const float*)d_in[8];
    const float* Wo = (const float*)d_in[9];
    const float* bo = (const float*)d_in[10];

    float* out  = (float*)d_out;                               // [B,S,D]
    float* attn = out + (size_t)BATCH * SEQ * D_MODEL;         // [B,H,S,S]

    const size_t MAT = (size_t)BATCH * SEQ * D_MODEL;          // 4096*1024
    float* ws  = (float*)d_ws;
    float* Qp  = ws;
    float* Kp  = Qp + MAT;
    float* Vp  = Kp + MAT;
    float* ctx = Vp + MAT;

    const int M = BATCH * SEQ;                                 // 4096
    dim3 gblk(256), ggrid(D_MODEL / 128, M / 128);

    gemm_bias_kernel<<<ggrid, gblk, 0, stream>>>(query, Wq, bq, Qp);
    gemm_bias_kernel<<<ggrid, gblk, 0, stream>>>(key,   Wk, bk, Kp);
    gemm_bias_kernel<<<ggrid, gblk, 0, stream>>>(value, Wv, bv, Vp);

    dim3 agrid(SEQ / TQ, NUM_HEADS, BATCH);
    attn_kernel<<<agrid, 512, 0, stream>>>(Qp, Kp, Vp, attn, ctx);

    gemm_bias_kernel<<<ggrid, gblk, 0, stream>>>(ctx, Wo, bo, out);
}

// Round 4
// 1786.102 us; speedup vs baseline: 4.0976x; 4.0976x over previous
//
#include <hip/hip_runtime.h>

#define D_MODEL 1024
#define NUM_HEADS 16
#define D_K 64
#define BATCH 2
#define SEQ 2048
#define TQ 8

// ---------------------------------------------------------------------------
// Tiled fp32 GEMM: C[M,1024] = A[M,1024] @ W[1024,1024] + bias[1024]
// 128x128 tile per 256-thread block, 8x8 micro-tile per thread, K-tile = 16.
// KT=true: write output transposed into Kt[b][h][d][s] layout (for attention's
// coalesced K reads). Scalar stores, but the block collectively covers whole
// cache lines so L2 write-combines them.
// ---------------------------------------------------------------------------
template <bool KT>
__global__ __launch_bounds__(256, 2)
void gemm_bias_kernel(const float* __restrict__ A, const float* __restrict__ W,
                      const float* __restrict__ bias, float* __restrict__ C) {
    __shared__ float As[16][128];   // [k][row] (transposed for broadcast reads)
    __shared__ float Bs[16][128];   // [k][col]

    const int tid = threadIdx.x;
    const int tx = tid & 15;        // 0..15 -> col group (8 cols each)
    const int ty = tid >> 4;        // 0..15 -> row group (8 rows each)
    const int rowBase = blockIdx.y * 128;
    const int colBase = blockIdx.x * 128;

    const int ar = tid >> 1;            // 0..127 A-tile row
    const int ac = (tid & 1) * 8;       // 0 or 8  A-tile k-offset
    const int br = tid >> 4;            // 0..15  W-tile k-row
    const int bc = (tid & 15) * 8;      // 0..120 W-tile col

    float acc[8][8] = {};

    for (int k0 = 0; k0 < D_MODEL; k0 += 16) {
        const float* Ar = A + (size_t)(rowBase + ar) * D_MODEL + k0 + ac;
        const float* Wr = W + (size_t)(k0 + br) * D_MODEL + colBase + bc;
        const float4 a0 = *(const float4*)(Ar + 0);
        const float4 a1 = *(const float4*)(Ar + 4);
        const float4 b0 = *(const float4*)(Wr + 0);
        const float4 b1 = *(const float4*)(Wr + 4);
        __syncthreads();   // previous iteration's LDS reads must finish
        As[ac + 0][ar] = a0.x; As[ac + 1][ar] = a0.y;
        As[ac + 2][ar] = a0.z; As[ac + 3][ar] = a0.w;
        As[ac + 4][ar] = a1.x; As[ac + 5][ar] = a1.y;
        As[ac + 6][ar] = a1.z; As[ac + 7][ar] = a1.w;
        *(float4*)&Bs[br][bc + 0] = b0;
        *(float4*)&Bs[br][bc + 4] = b1;
        __syncthreads();
#pragma unroll
        for (int kk = 0; kk < 16; ++kk) {
            const float4 xa0 = *(const float4*)&As[kk][ty * 8 + 0];
            const float4 xa1 = *(const float4*)&As[kk][ty * 8 + 4];
            const float4 xb0 = *(const float4*)&Bs[kk][tx * 8 + 0];
            const float4 xb1 = *(const float4*)&Bs[kk][tx * 8 + 4];
            const float a[8] = {xa0.x, xa0.y, xa0.z, xa0.w, xa1.x, xa1.y, xa1.z, xa1.w};
            const float bcol[8] = {xb0.x, xb0.y, xb0.z, xb0.w, xb1.x, xb1.y, xb1.z, xb1.w};
#pragma unroll
            for (int i = 0; i < 8; ++i)
#pragma unroll
                for (int j = 0; j < 8; ++j)
                    acc[i][j] += a[i] * bcol[j];
        }
    }

    if constexpr (!KT) {
        const float4 bb0 = *(const float4*)(bias + colBase + tx * 8 + 0);
        const float4 bb1 = *(const float4*)(bias + colBase + tx * 8 + 4);
#pragma unroll
        for (int i = 0; i < 8; ++i) {
            float4 o0, o1;
            o0.x = acc[i][0] + bb0.x; o0.y = acc[i][1] + bb0.y;
            o0.z = acc[i][2] + bb0.z; o0.w = acc[i][3] + bb0.w;
            o1.x = acc[i][4] + bb1.x; o1.y = acc[i][5] + bb1.y;
            o1.z = acc[i][6] + bb1.z; o1.w = acc[i][7] + bb1.w;
            float* Cr = C + (size_t)(rowBase + ty * 8 + i) * D_MODEL + colBase + tx * 8;
            *(float4*)(Cr + 0) = o0;
            *(float4*)(Cr + 4) = o1;
        }
    } else {
        // transposed epilogue: C is Kt[((b*16+h)*64+d)*2048 + s]
#pragma unroll
        for (int j = 0; j < 8; ++j) {
            const int col = colBase + tx * 8 + j;     // 0..1023
            const int h = col >> 6, d = col & 63;
            const float bj = bias[col];
#pragma unroll
            for (int i = 0; i < 8; ++i) {
                const int row = rowBase + ty * 8 + i; // 0..4095
                const int b = row >> 11, s = row & 2047;
                C[(((size_t)(b * NUM_HEADS + h)) * 64 + d) * SEQ + s] = acc[i][j] + bj;
            }
        }
    }
}

// ---------------------------------------------------------------------------
// Attention: one block per (b, h, 8 query rows). 512 threads (8 waves).
// K is consumed in [b][h][d][s] layout -> thread owns 4 CONSECUTIVE k columns
// (kb = tid*4); every global K load is a wave-contiguous 1024B float4 stream.
// ---------------------------------------------------------------------------
__global__ __launch_bounds__(512, 2)
void attn_kernel(const float* __restrict__ Qp, const float* __restrict__ Ktp,
                 const float* __restrict__ Vp, float* __restrict__ attn,
                 float* __restrict__ ctx) {
    const int b  = blockIdx.z;
    const int h  = blockIdx.y;
    const int q0 = blockIdx.x * TQ;
    const int tid  = threadIdx.x;
    const int lane = tid & 63;
    const int wid  = tid >> 6;

    __shared__ float qv[TQ][64];        // 2 KB
    __shared__ float sc[TQ][SEQ];       // 64 KB un-normalized exp; reused as PV-reduce buffer
    __shared__ float wredm[TQ][8];      // per-wave max partials
    __shared__ float wreds[TQ][8];      // per-wave sum partials

    // ---- load 8 query vectors (512 threads = 8*64 elements) ----
    {
        const int q = tid >> 6, d = tid & 63;
        qv[q][d] = Qp[((size_t)(b * SEQ + q0 + q)) * D_MODEL + h * 64 + d];
    }
    __syncthreads();

    // ---- scores: thread owns 4 consecutive k columns for all 8 q rows ----
    float loc[TQ][4];
#pragma unroll
    for (int q = 0; q < TQ; ++q)
#pragma unroll
        for (int j = 0; j < 4; ++j) loc[q][j] = 0.f;

    const float* Ktb = Ktp + ((size_t)(b * NUM_HEADS + h)) * 64 * SEQ; // [64][2048]
    const int kb = tid * 4;
#pragma unroll 2
    for (int dc = 0; dc < 64; dc += 4) {
        float4 qreg[TQ];
#pragma unroll
        for (int q = 0; q < TQ; ++q) qreg[q] = *(const float4*)&qv[q][dc];  // LDS broadcast
#pragma unroll
        for (int dd = 0; dd < 4; ++dd) {
            const float4 kv = *(const float4*)(Ktb + (size_t)(dc + dd) * SEQ + kb);
#pragma unroll
            for (int q = 0; q < TQ; ++q) {
                const float qq = (dd == 0) ? qreg[q].x : (dd == 1) ? qreg[q].y
                               : (dd == 2) ? qreg[q].z : qreg[q].w;   // static after unroll
                loc[q][0] += qq * kv.x;
                loc[q][1] += qq * kv.y;
                loc[q][2] += qq * kv.z;
                loc[q][3] += qq * kv.w;
            }
        }
    }
    const float scale = 0.125f;   // 1/sqrt(64)
#pragma unroll
    for (int q = 0; q < TQ; ++q)
#pragma unroll
        for (int j = 0; j < 4; ++j) loc[q][j] *= scale;

    // ---- row max: thread-local -> wave shuffle -> cross-wave via LDS ----
    float m[TQ];
#pragma unroll
    for (int q = 0; q < TQ; ++q) {
        float lm = fmaxf(fmaxf(loc[q][0], loc[q][1]), fmaxf(loc[q][2], loc[q][3]));
#pragma unroll
        for (int st = 32; st > 0; st >>= 1) lm = fmaxf(lm, __shfl_xor(lm, st, 64));
        if (lane == 0) wredm[q][wid] = lm;
    }
    __syncthreads();
#pragma unroll
    for (int q = 0; q < TQ; ++q) {
        float mm = wredm[q][0];
#pragma unroll
        for (int w = 1; w < 8; ++w) mm = fmaxf(mm, wredm[q][w]);
        m[q] = mm;
    }

    // ---- exp, stash un-normalized in LDS (float4), row-sum ----
#pragma unroll
    for (int q = 0; q < TQ; ++q) {
        float4 e4;
        e4.x = __expf(loc[q][0] - m[q]);
        e4.y = __expf(loc[q][1] - m[q]);
        e4.z = __expf(loc[q][2] - m[q]);
        e4.w = __expf(loc[q][3] - m[q]);
        loc[q][0] = e4.x; loc[q][1] = e4.y; loc[q][2] = e4.z; loc[q][3] = e4.w;
        *(float4*)&sc[q][kb] = e4;
        float ls = e4.x + e4.y + e4.z + e4.w;
#pragma unroll
        for (int st = 32; st > 0; st >>= 1) ls += __shfl_xor(ls, st, 64);
        if (lane == 0) wreds[q][wid] = ls;
    }
    __syncthreads();
    float inv[TQ];
#pragma unroll
    for (int q = 0; q < TQ; ++q) {
        float ss = wreds[q][0];
#pragma unroll
        for (int w = 1; w < 8; ++w) ss += wreds[q][w];
        inv[q] = 1.0f / ss;
    }

    // ---- write normalized attn (float4: 1024B per wave-instr) ----
#pragma unroll
    for (int q = 0; q < TQ; ++q) {
        const size_t base = (((size_t)(b * NUM_HEADS + h)) * SEQ + (q0 + q)) * (size_t)SEQ;
        float4 o;
        o.x = loc[q][0] * inv[q]; o.y = loc[q][1] * inv[q];
        o.z = loc[q][2] * inv[q]; o.w = loc[q][3] * inv[q];
        *(float4*)(attn + base + kb) = o;
    }

    // ---- fused PV: thread owns 8q x 4d over a 64-wide k slice ----
    const int d4 = (tid & 15) * 4;      // 0..60
    const int kg = tid >> 4;            // 0..31 k-group, 64 k each
    float acc[TQ][4];
#pragma unroll
    for (int q = 0; q < TQ; ++q)
#pragma unroll
        for (int j = 0; j < 4; ++j) acc[q][j] = 0.f;

    const float* Vb = Vp + ((size_t)b * SEQ) * D_MODEL + h * 64 + d4;
#pragma unroll 4
    for (int ks = 0; ks < 64; ks += 4) {
        const int k = kg * 64 + ks;
        const float4 vv0 = *(const float4*)(Vb + (size_t)(k + 0) * D_MODEL);
        const float4 vv1 = *(const float4*)(Vb + (size_t)(k + 1) * D_MODEL);
        const float4 vv2 = *(const float4*)(Vb + (size_t)(k + 2) * D_MODEL);
        const float4 vv3 = *(const float4*)(Vb + (size_t)(k + 3) * D_MODEL);
#pragma unroll
        for (int q = 0; q < TQ; ++q) {
            const float4 p = *(const float4*)&sc[q][k];
            acc[q][0] += p.x * vv0.x + p.y * vv1.x + p.z * vv2.x + p.w * vv3.x;
            acc[q][1] += p.x * vv0.y + p.y * vv1.y + p.z * vv2.y + p.w * vv3.y;
            acc[q][2] += p.x * vv0.z + p.y * vv1.z + p.z * vv2.z + p.w * vv3.z;
            acc[q][3] += p.x * vv0.w + p.y * vv1.w + p.z * vv2.w + p.w * vv3.w;
        }
    }

    // ---- reduce the 32 k-groups through LDS (reuse sc: exactly 16384 floats) ----
    __syncthreads();   // all sc reads done
    float* red = &sc[0][0];             // red[kg][q][d] = [32][8][64]
#pragma unroll
    for (int q = 0; q < TQ; ++q) {
        float4 o;
        o.x = acc[q][0]; o.y = acc[q][1]; o.z = acc[q][2]; o.w = acc[q][3];
        *(float4*)&red[((size_t)kg * TQ + q) * 64 + d4] = o;
    }
    __syncthreads();
    {
        const int q = tid >> 6, d = tid & 63;
        float s = 0.f;
#pragma unroll
        for (int g = 0; g < 32; ++g) s += red[((size_t)g * TQ + q) * 64 + d];
        ctx[((size_t)(b * SEQ + q0 + q)) * D_MODEL + h * 64 + d] = s * inv[q];
    }
}

// ---------------------------------------------------------------------------
extern "C" void kernel_launch(void* const* d_in, const int* in_sizes, int n_in,
                              void* d_out, int out_size, void* d_ws, size_t ws_size,
                              hipStream_t stream) {
    const float* query = (const float*)d_in[0];
    const float* key   = (const float*)d_in[1];
    const float* value = (const float*)d_in[2];
    const float* Wq = (const float*)d_in[3];
    const float* bq = (const float*)d_in[4];
    const float* Wk = (const float*)d_in[5];
    const float* bk = (const float*)d_in[6];
    const float* Wv = (const float*)d_in[7];
    const float* bv = (const float*)d_in[8];
    const float* Wo = (const float*)d_in[9];
    const float* bo = (const float*)d_in[10];

    float* out  = (float*)d_out;                               // [B,S,D]
    float* attn = out + (size_t)BATCH * SEQ * D_MODEL;         // [B,H,S,S]

    const size_t MAT = (size_t)BATCH * SEQ * D_MODEL;          // 4096*1024
    float* ws  = (float*)d_ws;
    float* Qp  = ws;
    float* Ktp = Qp + MAT;      // K in [b][h][d][s] layout
    float* Vp  = Ktp + MAT;
    float* ctx = Vp + MAT;

    const int M = BATCH * SEQ;                                 // 4096
    dim3 gblk(256), ggrid(D_MODEL / 128, M / 128);

    gemm_bias_kernel<false><<<ggrid, gblk, 0, stream>>>(query, Wq, bq, Qp);
    gemm_bias_kernel<true ><<<ggrid, gblk, 0, stream>>>(key,   Wk, bk, Ktp);
    gemm_bias_kernel<false><<<ggrid, gblk, 0, stream>>>(value, Wv, bv, Vp);

    dim3 agrid(SEQ / TQ, NUM_HEADS, BATCH);
    attn_kernel<<<agrid, 512, 0, stream>>>(Qp, Ktp, Vp, attn, ctx);

    gemm_bias_kernel<false><<<ggrid, gblk, 0, stream>>>(ctx, Wo, bo, out);
}